// Round 7
// baseline (83.404 us; speedup 1.0000x reference)
//
#include <hip/hip_runtime.h>

#define ALPHA 0.3f
#define NT    50
#define B_    16
#define S_    160
#define RR    40
#define Q_    (RR / 4)            // 10 float4 per rel row-pair
#define NROW  (B_ * S_)           // 2560
#define NPAIR (B_ * S_ * S_)      // 409600
#define NSEG  (NT * NT)           // 2500
#define NREL  (NPAIR * RR)        // 16384000
#define NREL4 (NPAIR * Q_)        // 4096000 float4 of rel
#define NARC4 (NPAIR / 4)         // 102400 float4 of arc
#define NCOL  (NT * RR + NT)      // 2050 compact floats per C row
#define CW    2052                // padded C row stride (floats), 8208B (16B-aligned)

__global__ void zero_tab(float* __restrict__ tab, int n) {
    int i = blockIdx.x * blockDim.x + threadIdx.x;
    if (i < n) tab[i] = 0.0f;
}

// ---- per-batch position lists: deterministic counting sort of adds[b][:] ----
__global__ void build_lists(const int* __restrict__ adds,
                            int* __restrict__ colstart,   // [B_][64]
                            int* __restrict__ collist) {  // [B_][S_]
    __shared__ int tags[S_];
    __shared__ int cnt[NT];
    __shared__ int start[NT + 1];
    int b   = blockIdx.x;
    int tid = threadIdx.x;
    if (tid < S_) tags[tid] = adds[b * S_ + tid];
    __syncthreads();
    if (tid < NT) {
        int c = 0;
        for (int i = 0; i < S_; i++) c += (tags[i] == tid);
        cnt[tid] = c;
    }
    __syncthreads();
    if (tid == 0) {
        int s = 0;
        for (int t = 0; t < NT; t++) { start[t] = s; s += cnt[t]; }
        start[NT] = s;
    }
    __syncthreads();
    if (tid <= NT) colstart[b * 64 + tid] = start[tid];
    if (tid < NT) {
        int slot = start[tid];
        for (int i = 0; i < S_; i++)
            if (tags[i] == tid) collist[b * S_ + slot++] = i;
    }
}

// ---- stage 1: one 128-thread block per (b,p1) row; register gather, NO atomics.
// 2560 blocks / 256 CU = 10 blocks/CU < 16-block residency cap -> one full round.
// TO_C=1: write compact partial row to C.  TO_C=0: atomic-flush to tab (fallback).
template <int TO_C>
__global__ __launch_bounds__(128) void stage1(const float* __restrict__ a_arc,
                                              const float4* __restrict__ a_rel4,
                                              const int* __restrict__ adds,
                                              const int* __restrict__ colstart,
                                              const int* __restrict__ collist,
                                              float* __restrict__ C,
                                              float* __restrict__ tab_arc,
                                              float* __restrict__ tab_rel) {
    __shared__ int s_start[NT + 1];
    __shared__ int s_list[S_];
    int row = blockIdx.x;            // b*S_ + p1
    int b   = row / S_;
    int tid = threadIdx.x;
    for (int i = tid; i <= NT; i += 128) s_start[i] = colstart[b * 64 + i];
    for (int i = tid; i < S_; i += 128) s_list[i] = collist[b * S_ + i];
    __syncthreads();

    const float4* arow  = a_rel4 + (size_t)row * (S_ * Q_);
    const float*  aarow = a_arc + (size_t)row * S_;
    int t1 = TO_C ? 0 : adds[row];

    // rel: 500 float4 cells (t2, q), ~4 per thread
    for (int cell = tid; cell < NT * Q_; cell += 128) {
        int t2 = cell / Q_;
        int q  = cell - t2 * Q_;
        float4 acc = make_float4(0.f, 0.f, 0.f, 0.f);
        int e1 = s_start[t2 + 1];
        for (int e = s_start[t2]; e < e1; ++e) {
            float4 v = arow[s_list[e] * Q_ + q];
            acc.x += v.x; acc.y += v.y; acc.z += v.z; acc.w += v.w;
        }
        if (TO_C) {
            ((float4*)(C + (size_t)row * CW))[cell] = acc;
        } else {
            float* dst = tab_rel + (size_t)t1 * (NT * RR) + cell * 4;
            atomicAdd(dst + 0, acc.x); atomicAdd(dst + 1, acc.y);
            atomicAdd(dst + 2, acc.z); atomicAdd(dst + 3, acc.w);
        }
    }
    // arc: 50 cells
    if (tid < NT) {
        float acc = 0.f;
        int e1 = s_start[tid + 1];
        for (int e = s_start[tid]; e < e1; ++e) acc += aarow[s_list[e]];
        if (TO_C) C[(size_t)row * CW + NT * RR + tid] = acc;
        else      atomicAdd(tab_arc + t1 * NT + tid, acc);
    }
}

// ---- stage 2: reduce C rows grouped by t1 via per-batch lists, NO atomics ----
__global__ __launch_bounds__(256) void stage2(const float* __restrict__ C,
                                              const int* __restrict__ colstart,
                                              const int* __restrict__ collist,
                                              float* __restrict__ tab_arc,
                                              float* __restrict__ tab_rel) {
    int t1 = blockIdx.y;
    int c  = blockIdx.x * 256 + threadIdx.x;
    if (c >= NCOL) return;
    float acc = 0.f;
    for (int b = 0; b < B_; b++) {
        int s0 = colstart[b * 64 + t1], s1 = colstart[b * 64 + t1 + 1];
        for (int j = s0; j < s1; j++) {
            int row = b * S_ + collist[b * S_ + j];
            acc += C[(size_t)row * CW + c];
        }
    }
    if (c < NT * RR) tab_rel[t1 * (NT * RR) + c] = acc;
    else             tab_arc[t1 * NT + (c - NT * RR)] = acc;
}

// ---- fused flat apply: grid-stride, 2048 blocks = exactly 8/CU, no LDS/syncs ----
__global__ __launch_bounds__(256) void apply_flat(const float* __restrict__ s_arc,
                                                  const float4* __restrict__ s_rel4,
                                                  const int* __restrict__ pos,
                                                  const float* __restrict__ tab_arc,
                                                  const float4* __restrict__ tab_rel4,
                                                  float* __restrict__ out_arc,
                                                  float4* __restrict__ out_rel4) {
    const int nthreads = gridDim.x * blockDim.x;
    for (int t = blockIdx.x * blockDim.x + threadIdx.x;
         t < NREL4 + NARC4; t += nthreads) {
        if (t < NREL4) {
            int pair = t / Q_;
            int q    = t - pair * Q_;
            int b    = pair / (S_ * S_);
            int rem  = pair - b * (S_ * S_);
            int p1   = rem / S_;
            int p2   = rem - p1 * S_;
            int key  = pos[b * S_ + p1] * NT + pos[b * S_ + p2];
            float4 sv = s_rel4[t];
            float4 tv = tab_rel4[key * Q_ + q];
            float4 o;
            o.x = sv.x + ALPHA * tv.x;
            o.y = sv.y + ALPHA * tv.y;
            o.z = sv.z + ALPHA * tv.z;
            o.w = sv.w + ALPHA * tv.w;
            out_rel4[t] = o;
        } else {
            int j   = t - NREL4;          // float4 index into arc
            int e0  = j * 4;
            int b   = e0 / (S_ * S_);
            int rem = e0 - b * (S_ * S_);
            int p1  = rem / S_;
            int p2  = rem - p1 * S_;      // multiple of 4, p2+3 <= 159
            const int* posb = pos + b * S_;
            int base = posb[p1] * NT;
            float4 sv = ((const float4*)s_arc)[j];
            float4 o;
            o.x = sv.x + ALPHA * tab_arc[base + posb[p2 + 0]];
            o.y = sv.y + ALPHA * tab_arc[base + posb[p2 + 1]];
            o.z = sv.z + ALPHA * tab_arc[base + posb[p2 + 2]];
            o.w = sv.w + ALPHA * tab_arc[base + posb[p2 + 3]];
            ((float4*)out_arc)[j] = o;
        }
    }
}

extern "C" void kernel_launch(void* const* d_in, const int* in_sizes, int n_in,
                              void* d_out, int out_size, void* d_ws, size_t ws_size,
                              hipStream_t stream) {
    const float*  a_arc = (const float*)d_in[0];
    const float4* a_rel = (const float4*)d_in[1];
    const float*  s_arc = (const float*)d_in[2];
    const float4* s_rel = (const float4*)d_in[3];
    const int*    adds  = (const int*)d_in[4];
    const int*    pos   = (const int*)d_in[5];

    // workspace layout
    float* tab_arc  = (float*)d_ws;                    // NSEG
    float* tab_rel  = tab_arc + NSEG;                  // NSEG*RR
    int*   colstart = (int*)(tab_rel + NSEG * RR);     // B_*64
    int*   collist  = colstart + B_ * 64;              // B_*S_
    float* C        = (float*)(collist + B_ * S_);     // NROW*CW
    C = (float*)(((uintptr_t)C + 15) & ~(uintptr_t)15);

    size_t need_lists = (size_t)(NSEG * (RR + 1)) * 4
                      + (size_t)(B_ * 64 + B_ * S_) * 4 + 16;
    size_t need_full  = need_lists + (size_t)NROW * CW * 4;

    float*  out_arc = (float*)d_out;                   // NPAIR
    float4* out_rel = (float4*)(out_arc + NPAIR);      // NREL/4

    const int BLK = 256;

    build_lists<<<B_, 192, 0, stream>>>(adds, colstart, collist);

    if (ws_size >= need_full) {
        // deterministic two-stage path, zero atomics anywhere
        stage1<1><<<NROW, 128, 0, stream>>>(a_arc, a_rel, adds, colstart, collist,
                                            C, nullptr, nullptr);
        dim3 g2((NCOL + 255) / 256, NT);
        stage2<<<g2, 256, 0, stream>>>(C, colstart, collist, tab_arc, tab_rel);
    } else {
        int n_tab = NSEG * (RR + 1);
        zero_tab<<<(n_tab + BLK - 1) / BLK, BLK, 0, stream>>>(tab_arc, n_tab);
        stage1<0><<<NROW, 128, 0, stream>>>(a_arc, a_rel, adds, colstart, collist,
                                            nullptr, tab_arc, tab_rel);
    }

    apply_flat<<<2048, 256, 0, stream>>>(s_arc, s_rel, pos, tab_arc,
                                         (const float4*)tab_rel, out_arc, out_rel);
}

// Round 8
// 81.723 us; speedup vs baseline: 1.0206x; 1.0206x over previous
//
#include <hip/hip_runtime.h>

#define ALPHA 0.3f
#define NT    50
#define B_    16
#define S_    160
#define RR    40
#define Q_    (RR / 4)            // 10 float4 per rel pair
#define NROW  (B_ * S_)           // 2560
#define NPAIR (B_ * S_ * S_)      // 409600
#define NSEG  (NT * NT)           // 2500
#define NREL4 (NPAIR * Q_)        // 4096000 float4 of rel
#define NARC4 (NPAIR / 4)         // 102400 float4 of arc
#define NCOL  (NT * RR + NT)      // 2050 compact floats per C row
#define CW    2052                // padded C row stride (floats), 8208B (16B-aligned)

#define REL_BLOCKS 2000
#define REL_STRIDE (REL_BLOCKS * 256)   // 512000 ; x8 iters = 4096000 = NREL4 exactly
#define ARC_BLOCKS 50
#define ARC_STRIDE (ARC_BLOCKS * 256)   // 12800  ; x8 iters = 102400 = NARC4 exactly

__global__ void zero_tab(float* __restrict__ tab, int n) {
    int i = blockIdx.x * blockDim.x + threadIdx.x;
    if (i < n) tab[i] = 0.0f;
}

// ---- per-batch position lists: deterministic counting sort of adds[b][:] ----
__global__ void build_lists(const int* __restrict__ adds,
                            int* __restrict__ colstart,   // [B_][64]
                            int* __restrict__ collist) {  // [B_][S_]
    __shared__ int tags[S_];
    __shared__ int cnt[NT];
    __shared__ int start[NT + 1];
    int b   = blockIdx.x;
    int tid = threadIdx.x;
    if (tid < S_) tags[tid] = adds[b * S_ + tid];
    __syncthreads();
    if (tid < NT) {
        int c = 0;
        for (int i = 0; i < S_; i++) c += (tags[i] == tid);
        cnt[tid] = c;
    }
    __syncthreads();
    if (tid == 0) {
        int s = 0;
        for (int t = 0; t < NT; t++) { start[t] = s; s += cnt[t]; }
        start[NT] = s;
    }
    __syncthreads();
    if (tid <= NT) colstart[b * 64 + tid] = start[tid];
    if (tid < NT) {
        int slot = start[tid];
        for (int i = 0; i < S_; i++)
            if (tags[i] == tid) collist[b * S_ + slot++] = i;
    }
}

// ---- stage 1 v2: stream whole row into LDS (unrolled, coalesced, high MLP),
// then gather-reduce from LDS. One 256-thread block per (b,p1) row. NO atomics.
template <int TO_C>
__global__ __launch_bounds__(256) void stage1(const float* __restrict__ a_arc,
                                              const float4* __restrict__ a_rel4,
                                              const int* __restrict__ adds,
                                              const int* __restrict__ colstart,
                                              const int* __restrict__ collist,
                                              float* __restrict__ C,
                                              float* __restrict__ tab_arc,
                                              float* __restrict__ tab_rel) {
    __shared__ float4 a_lds[S_ * Q_];     // 1600 float4 = 25600 B (whole rel row)
    __shared__ float4 aarc_lds[S_ / 4];   // 40 float4 (whole arc row)
    __shared__ int    s_start[NT + 1];
    __shared__ int    s_list[S_];
    int row = blockIdx.x;                 // b*S_ + p1
    int b   = row / S_;
    int tid = threadIdx.x;

    for (int i = tid; i <= NT; i += 256) s_start[i] = colstart[b * 64 + i];
    for (int i = tid; i < S_; i += 256)  s_list[i]  = collist[b * S_ + i];

    const float4* arow = a_rel4 + (size_t)row * (S_ * Q_);
#pragma unroll
    for (int k = 0; k < 7; ++k) {         // 7*256 = 1792 >= 1600
        int idx = k * 256 + tid;
        if (idx < S_ * Q_) a_lds[idx] = arow[idx];
    }
    if (tid < S_ / 4)
        aarc_lds[tid] = ((const float4*)(a_arc + (size_t)row * S_))[tid];
    __syncthreads();

    int t1 = TO_C ? 0 : adds[row];

    // rel: 500 cells (t2, q); gather from LDS
    for (int cell = tid; cell < NT * Q_; cell += 256) {
        int t2 = cell / Q_;
        int q  = cell - t2 * Q_;
        float4 acc = make_float4(0.f, 0.f, 0.f, 0.f);
        int e1 = s_start[t2 + 1];
        for (int e = s_start[t2]; e < e1; ++e) {
            float4 v = a_lds[s_list[e] * Q_ + q];
            acc.x += v.x; acc.y += v.y; acc.z += v.z; acc.w += v.w;
        }
        if (TO_C) {
            ((float4*)(C + (size_t)row * CW))[cell] = acc;
        } else {
            float* dst = tab_rel + (size_t)t1 * (NT * RR) + cell * 4;
            atomicAdd(dst + 0, acc.x); atomicAdd(dst + 1, acc.y);
            atomicAdd(dst + 2, acc.z); atomicAdd(dst + 3, acc.w);
        }
    }
    // arc: 50 cells
    if (tid < NT) {
        const float* aarcf = (const float*)aarc_lds;
        float acc = 0.f;
        int e1 = s_start[tid + 1];
        for (int e = s_start[tid]; e < e1; ++e) acc += aarcf[s_list[e]];
        if (TO_C) C[(size_t)row * CW + NT * RR + tid] = acc;
        else      atomicAdd(tab_arc + t1 * NT + tid, acc);
    }
}

// ---- stage 2: reduce C rows grouped by t1 via per-batch lists, NO atomics ----
__global__ __launch_bounds__(256) void stage2(const float* __restrict__ C,
                                              const int* __restrict__ colstart,
                                              const int* __restrict__ collist,
                                              float* __restrict__ tab_arc,
                                              float* __restrict__ tab_rel) {
    int t1 = blockIdx.y;
    int c  = blockIdx.x * 256 + threadIdx.x;
    if (c >= NCOL) return;
    float acc = 0.f;
    for (int b = 0; b < B_; b++) {
        int s0 = colstart[b * 64 + t1], s1 = colstart[b * 64 + t1 + 1];
        for (int j = s0; j < s1; j++) {
            int row = b * S_ + collist[b * S_ + j];
            acc += C[(size_t)row * CW + c];
        }
    }
    if (c < NT * RR) tab_rel[t1 * (NT * RR) + c] = acc;
    else             tab_arc[t1 * NT + (c - NT * RR)] = acc;
}

// key*Q_+q for a rel float4 index t
__device__ __forceinline__ int keyq(const int* __restrict__ pos, int t) {
    int pair = t / Q_;
    int q    = t - pair * Q_;
    int b    = pair / (S_ * S_);
    int rem  = pair - b * (S_ * S_);
    int p1   = rem / S_;
    int p2   = rem - p1 * S_;
    return (pos[b * S_ + p1] * NT + pos[b * S_ + p2]) * Q_ + q;
}

// ---- apply v2: compile-time trip counts, hand-batched loads for MLP ----
__global__ __launch_bounds__(256) void apply_v2(const float* __restrict__ s_arc,
                                                const float4* __restrict__ s_rel4,
                                                const int* __restrict__ pos,
                                                const float* __restrict__ tab_arc,
                                                const float4* __restrict__ tab_rel4,
                                                float* __restrict__ out_arc,
                                                float4* __restrict__ out_rel4) {
    int bid = blockIdx.x, tid = threadIdx.x;
    if (bid < REL_BLOCKS) {
        const int t0 = bid * 256 + tid;
#pragma unroll
        for (int half = 0; half < 2; ++half) {
            const int ta = t0 + (half * 4 + 0) * REL_STRIDE;
            const int tb = t0 + (half * 4 + 1) * REL_STRIDE;
            const int tc = t0 + (half * 4 + 2) * REL_STRIDE;
            const int td = t0 + (half * 4 + 3) * REL_STRIDE;
            // batch 4 streaming loads
            float4 sv0 = s_rel4[ta];
            float4 sv1 = s_rel4[tb];
            float4 sv2 = s_rel4[tc];
            float4 sv3 = s_rel4[td];
            // batch 8 pos loads -> 4 table loads
            int k0 = keyq(pos, ta);
            int k1 = keyq(pos, tb);
            int k2 = keyq(pos, tc);
            int k3 = keyq(pos, td);
            float4 tv0 = tab_rel4[k0];
            float4 tv1 = tab_rel4[k1];
            float4 tv2 = tab_rel4[k2];
            float4 tv3 = tab_rel4[k3];
            float4 o0, o1, o2, o3;
            o0.x = sv0.x + ALPHA * tv0.x; o0.y = sv0.y + ALPHA * tv0.y;
            o0.z = sv0.z + ALPHA * tv0.z; o0.w = sv0.w + ALPHA * tv0.w;
            o1.x = sv1.x + ALPHA * tv1.x; o1.y = sv1.y + ALPHA * tv1.y;
            o1.z = sv1.z + ALPHA * tv1.z; o1.w = sv1.w + ALPHA * tv1.w;
            o2.x = sv2.x + ALPHA * tv2.x; o2.y = sv2.y + ALPHA * tv2.y;
            o2.z = sv2.z + ALPHA * tv2.z; o2.w = sv2.w + ALPHA * tv2.w;
            o3.x = sv3.x + ALPHA * tv3.x; o3.y = sv3.y + ALPHA * tv3.y;
            o3.z = sv3.z + ALPHA * tv3.z; o3.w = sv3.w + ALPHA * tv3.w;
            out_rel4[ta] = o0;
            out_rel4[tb] = o1;
            out_rel4[tc] = o2;
            out_rel4[td] = o3;
        }
    } else {
        const int j0 = (bid - REL_BLOCKS) * 256 + tid;
#pragma unroll
        for (int k = 0; k < 8; ++k) {
            int j   = j0 + k * ARC_STRIDE;
            int e0  = j * 4;
            int b   = e0 / (S_ * S_);
            int rem = e0 - b * (S_ * S_);
            int p1  = rem / S_;
            int p2  = rem - p1 * S_;          // multiple of 4
            const int* posb = pos + b * S_;
            int base = posb[p1] * NT;
            float4 sv = ((const float4*)s_arc)[j];
            float4 o;
            o.x = sv.x + ALPHA * tab_arc[base + posb[p2 + 0]];
            o.y = sv.y + ALPHA * tab_arc[base + posb[p2 + 1]];
            o.z = sv.z + ALPHA * tab_arc[base + posb[p2 + 2]];
            o.w = sv.w + ALPHA * tab_arc[base + posb[p2 + 3]];
            ((float4*)out_arc)[j] = o;
        }
    }
}

extern "C" void kernel_launch(void* const* d_in, const int* in_sizes, int n_in,
                              void* d_out, int out_size, void* d_ws, size_t ws_size,
                              hipStream_t stream) {
    const float*  a_arc = (const float*)d_in[0];
    const float4* a_rel = (const float4*)d_in[1];
    const float*  s_arc = (const float*)d_in[2];
    const float4* s_rel = (const float4*)d_in[3];
    const int*    adds  = (const int*)d_in[4];
    const int*    pos   = (const int*)d_in[5];

    // workspace layout
    float* tab_arc  = (float*)d_ws;                    // NSEG
    float* tab_rel  = tab_arc + NSEG;                  // NSEG*RR
    int*   colstart = (int*)(tab_rel + NSEG * RR);     // B_*64
    int*   collist  = colstart + B_ * 64;              // B_*S_
    float* C        = (float*)(collist + B_ * S_);     // NROW*CW
    C = (float*)(((uintptr_t)C + 15) & ~(uintptr_t)15);

    size_t need_lists = (size_t)(NSEG * (RR + 1)) * 4
                      + (size_t)(B_ * 64 + B_ * S_) * 4 + 16;
    size_t need_full  = need_lists + (size_t)NROW * CW * 4;

    float*  out_arc = (float*)d_out;                   // NPAIR
    float4* out_rel = (float4*)(out_arc + NPAIR);      // NREL4

    const int BLK = 256;

    build_lists<<<B_, 192, 0, stream>>>(adds, colstart, collist);

    if (ws_size >= need_full) {
        // deterministic two-stage path, zero atomics anywhere
        stage1<1><<<NROW, 256, 0, stream>>>(a_arc, a_rel, adds, colstart, collist,
                                            C, nullptr, nullptr);
        dim3 g2((NCOL + 255) / 256, NT);
        stage2<<<g2, 256, 0, stream>>>(C, colstart, collist, tab_arc, tab_rel);
    } else {
        int n_tab = NSEG * (RR + 1);
        zero_tab<<<(n_tab + BLK - 1) / BLK, BLK, 0, stream>>>(tab_arc, n_tab);
        stage1<0><<<NROW, 256, 0, stream>>>(a_arc, a_rel, adds, colstart, collist,
                                            nullptr, tab_arc, tab_rel);
    }

    apply_v2<<<REL_BLOCKS + ARC_BLOCKS, 256, 0, stream>>>(
        s_arc, s_rel, pos, tab_arc, (const float4*)tab_rel, out_arc, out_rel);
}